// Round 1
// baseline (131.040 us; speedup 1.0000x reference)
//
#include <hip/hip_runtime.h>

// Loss = weighted-BCE(score)/m + Huber(geometry)/(8*n_pix)
// beta = 1 - sum(Y_true_score)/N_score factors out of the BCE sum, so a
// single pass computing S0=sum(yt), S1=sum(yt*log(yp)), S2=sum((1-yt)*log(1-yp)),
// SG=sum(huber) suffices; finalize combines them.

__global__ void loss_reduce(const float4* __restrict__ yts,
                            const float4* __restrict__ yps,
                            const float4* __restrict__ ytg,
                            const float4* __restrict__ ypg,
                            float* __restrict__ acc,
                            int n_s4, int n_g4) {
    float s0 = 0.f, s1 = 0.f, s2 = 0.f, sg = 0.f;
    const int tid    = blockIdx.x * blockDim.x + threadIdx.x;
    const int stride = gridDim.x * blockDim.x;

    // --- score arrays: BCE partial sums ---
    for (int i = tid; i < n_s4; i += stride) {
        float4 t = yts[i];
        float4 p = yps[i];
        s0 += (t.x + t.y) + (t.z + t.w);
        s1 += t.x * __logf(p.x) + t.y * __logf(p.y)
            + t.z * __logf(p.z) + t.w * __logf(p.w);
        s2 += (1.f - t.x) * __logf(1.f - p.x) + (1.f - t.y) * __logf(1.f - p.y)
            + (1.f - t.z) * __logf(1.f - p.z) + (1.f - t.w) * __logf(1.f - p.w);
    }

    // --- geometry arrays: Huber partial sum ---
    for (int i = tid; i < n_g4; i += stride) {
        float4 t = ytg[i];
        float4 p = ypg[i];
        float dx = fabsf(t.x - p.x);
        float dy = fabsf(t.y - p.y);
        float dz = fabsf(t.z - p.z);
        float dw = fabsf(t.w - p.w);
        float hx = (dx < 1.f) ? 0.5f * dx * dx : dx - 0.5f;
        float hy = (dy < 1.f) ? 0.5f * dy * dy : dy - 0.5f;
        float hz = (dz < 1.f) ? 0.5f * dz * dz : dz - 0.5f;
        float hw = (dw < 1.f) ? 0.5f * dw * dw : dw - 0.5f;
        sg += (hx + hy) + (hz + hw);
    }

    // --- wave (64-lane) butterfly reduce ---
    #pragma unroll
    for (int off = 32; off > 0; off >>= 1) {
        s0 += __shfl_down(s0, off);
        s1 += __shfl_down(s1, off);
        s2 += __shfl_down(s2, off);
        sg += __shfl_down(sg, off);
    }

    // --- cross-wave reduce in LDS, one atomicAdd set per block ---
    __shared__ float lds[4][4];  // up to 4 waves @ 256 threads
    const int wave = threadIdx.x >> 6;
    const int lane = threadIdx.x & 63;
    if (lane == 0) {
        lds[wave][0] = s0; lds[wave][1] = s1;
        lds[wave][2] = s2; lds[wave][3] = sg;
    }
    __syncthreads();
    if (threadIdx.x == 0) {
        float a0 = 0.f, a1 = 0.f, a2 = 0.f, a3 = 0.f;
        const int nw = blockDim.x >> 6;
        for (int w = 0; w < nw; ++w) {
            a0 += lds[w][0]; a1 += lds[w][1];
            a2 += lds[w][2]; a3 += lds[w][3];
        }
        atomicAdd(&acc[0], a0);
        atomicAdd(&acc[1], a1);
        atomicAdd(&acc[2], a2);
        atomicAdd(&acc[3], a3);
    }
}

__global__ void loss_finalize(const float* __restrict__ acc,
                              float* __restrict__ out,
                              float inv_n_score,   // 1 / N_score
                              float inv_m,         // 1 / m
                              float inv_geo_div) { // 1 / (8 * n_pix)
    const float S0 = acc[0];
    const float S1 = acc[1];
    const float S2 = acc[2];
    const float SG = acc[3];
    const float beta = 1.f - S0 * inv_n_score;
    const float loss_score = (-beta * S1 - (1.f - beta) * S2) * inv_m;
    const float loss_geo   = SG * inv_geo_div;  // LAMBDA_GEOMETRY = 1
    out[0] = loss_score + loss_geo;
}

extern "C" void kernel_launch(void* const* d_in, const int* in_sizes, int n_in,
                              void* d_out, int out_size, void* d_ws, size_t ws_size,
                              hipStream_t stream) {
    const float4* yts = (const float4*)d_in[0];
    const float4* yps = (const float4*)d_in[1];
    const float4* ytg = (const float4*)d_in[2];
    const float4* ypg = (const float4*)d_in[3];
    float* out = (float*)d_out;
    float* acc = (float*)d_ws;

    const int n_score = in_sizes[0];          // m*1*H*W = 2,097,152
    const int n_geo   = in_sizes[2];          // m*8*H*W = 16,777,216
    const int n_s4 = n_score / 4;
    const int n_g4 = n_geo / 4;

    // Shapes per reference setup: m=128, n_c=8, n_pix = m*H*W = n_score.
    const float inv_n_score = 1.f / (float)n_score;
    const float inv_m       = 1.f / 128.f;
    const float inv_geo_div = 1.f / (8.f * (float)n_score);

    // d_ws is NOT re-poisoned between replays — zero our accumulators each call.
    hipMemsetAsync(acc, 0, 4 * sizeof(float), stream);

    const int threads = 256;
    const int blocks  = 2048;  // grid-stride; ~memory-bound cap per G11
    loss_reduce<<<blocks, threads, 0, stream>>>(yts, yps, ytg, ypg, acc, n_s4, n_g4);
    loss_finalize<<<1, 1, 0, stream>>>(acc, out, inv_n_score, inv_m, inv_geo_div);
}

// Round 2
// 31.651 us; speedup vs baseline: 4.1401x; 4.1401x over previous
//
#include <hip/hip_runtime.h>

// Loss = weighted-BCE(score)/m + Huber(geometry)/(8*n_pix), single fused pass.
// beta = 1 - sum(Y_true_score)/N factors out: S0=sum(yt), S1=sum(yt*log(yp)),
// S2=sum((1-yt)*log(1-yp)), SG=sum(huber); finalize combines.
//
// Round-2 changes vs round-1 (140us, 531 GB/s, latency-bound):
//  - geometry loop: 4-deep batched loads (8 global_load_dwordx4 in flight
//    per wave before any s_waitcnt) -> ~4x memory-level parallelism
//  - no global atomics: per-block partial float4 -> d_ws, second kernel reduces
//    (removes 8192 serialized same-cache-line cross-XCD atomic fadds)

#define THREADS 256

__global__ __launch_bounds__(THREADS) void
loss_reduce(const float4* __restrict__ yts,
            const float4* __restrict__ yps,
            const float4* __restrict__ ytg,
            const float4* __restrict__ ypg,
            float4* __restrict__ partial,
            int n_s4, int n_g4) {
    const int tid = blockIdx.x * THREADS + threadIdx.x;
    const int T   = gridDim.x * THREADS;

    float s0 = 0.f, s1 = 0.f, s2 = 0.f, sg = 0.f;

    // --- score arrays: BCE partial sums (1/9 of traffic) ---
    for (int i = tid; i < n_s4; i += T) {
        float4 t = yts[i];
        float4 p = yps[i];
        s0 += (t.x + t.y) + (t.z + t.w);
        s1 += t.x * __logf(p.x) + t.y * __logf(p.y)
            + t.z * __logf(p.z) + t.w * __logf(p.w);
        s2 += (1.f - t.x) * __logf(1.f - p.x) + (1.f - t.y) * __logf(1.f - p.y)
            + (1.f - t.z) * __logf(1.f - p.z) + (1.f - t.w) * __logf(1.f - p.w);
    }

    // --- geometry arrays: Huber, 4-deep load batches for MLP ---
    int i = tid;
    for (; i + 3 * T < n_g4; i += 4 * T) {
        // issue all 8 loads before consuming any
        float4 t0 = ytg[i];
        float4 t1 = ytg[i + T];
        float4 t2 = ytg[i + 2 * T];
        float4 t3 = ytg[i + 3 * T];
        float4 p0 = ypg[i];
        float4 p1 = ypg[i + T];
        float4 p2 = ypg[i + 2 * T];
        float4 p3 = ypg[i + 3 * T];

        #pragma unroll
        for (int k = 0; k < 4; ++k) {
            float4 t = (k == 0) ? t0 : (k == 1) ? t1 : (k == 2) ? t2 : t3;
            float4 p = (k == 0) ? p0 : (k == 1) ? p1 : (k == 2) ? p2 : p3;
            float dx = fabsf(t.x - p.x);
            float dy = fabsf(t.y - p.y);
            float dz = fabsf(t.z - p.z);
            float dw = fabsf(t.w - p.w);
            float hx = (dx < 1.f) ? 0.5f * dx * dx : dx - 0.5f;
            float hy = (dy < 1.f) ? 0.5f * dy * dy : dy - 0.5f;
            float hz = (dz < 1.f) ? 0.5f * dz * dz : dz - 0.5f;
            float hw = (dw < 1.f) ? 0.5f * dw * dw : dw - 0.5f;
            sg += (hx + hy) + (hz + hw);
        }
    }
    for (; i < n_g4; i += T) {  // tail (empty for the reference shape)
        float4 t = ytg[i];
        float4 p = ypg[i];
        float dx = fabsf(t.x - p.x);
        float dy = fabsf(t.y - p.y);
        float dz = fabsf(t.z - p.z);
        float dw = fabsf(t.w - p.w);
        float hx = (dx < 1.f) ? 0.5f * dx * dx : dx - 0.5f;
        float hy = (dy < 1.f) ? 0.5f * dy * dy : dy - 0.5f;
        float hz = (dz < 1.f) ? 0.5f * dz * dz : dz - 0.5f;
        float hw = (dw < 1.f) ? 0.5f * dw * dw : dw - 0.5f;
        sg += (hx + hy) + (hz + hw);
    }

    // --- wave (64-lane) butterfly reduce ---
    #pragma unroll
    for (int off = 32; off > 0; off >>= 1) {
        s0 += __shfl_down(s0, off);
        s1 += __shfl_down(s1, off);
        s2 += __shfl_down(s2, off);
        sg += __shfl_down(sg, off);
    }

    // --- cross-wave reduce in LDS, one float4 store per block ---
    __shared__ float lds[4][4];
    const int wave = threadIdx.x >> 6;
    const int lane = threadIdx.x & 63;
    if (lane == 0) {
        lds[wave][0] = s0; lds[wave][1] = s1;
        lds[wave][2] = s2; lds[wave][3] = sg;
    }
    __syncthreads();
    if (threadIdx.x == 0) {
        float4 r;
        r.x = lds[0][0] + lds[1][0] + lds[2][0] + lds[3][0];
        r.y = lds[0][1] + lds[1][1] + lds[2][1] + lds[3][1];
        r.z = lds[0][2] + lds[1][2] + lds[2][2] + lds[3][2];
        r.w = lds[0][3] + lds[1][3] + lds[2][3] + lds[3][3];
        partial[blockIdx.x] = r;
    }
}

__global__ __launch_bounds__(THREADS) void
loss_finalize(const float4* __restrict__ partial, int nblocks,
              float* __restrict__ out,
              float inv_n_score, float inv_m, float inv_geo_div) {
    float s0 = 0.f, s1 = 0.f, s2 = 0.f, sg = 0.f;
    for (int i = threadIdx.x; i < nblocks; i += THREADS) {
        float4 v = partial[i];
        s0 += v.x; s1 += v.y; s2 += v.z; sg += v.w;
    }
    #pragma unroll
    for (int off = 32; off > 0; off >>= 1) {
        s0 += __shfl_down(s0, off);
        s1 += __shfl_down(s1, off);
        s2 += __shfl_down(s2, off);
        sg += __shfl_down(sg, off);
    }
    __shared__ float lds[4][4];
    const int wave = threadIdx.x >> 6;
    const int lane = threadIdx.x & 63;
    if (lane == 0) {
        lds[wave][0] = s0; lds[wave][1] = s1;
        lds[wave][2] = s2; lds[wave][3] = sg;
    }
    __syncthreads();
    if (threadIdx.x == 0) {
        const float S0 = lds[0][0] + lds[1][0] + lds[2][0] + lds[3][0];
        const float S1 = lds[0][1] + lds[1][1] + lds[2][1] + lds[3][1];
        const float S2 = lds[0][2] + lds[1][2] + lds[2][2] + lds[3][2];
        const float SG = lds[0][3] + lds[1][3] + lds[2][3] + lds[3][3];
        const float beta = 1.f - S0 * inv_n_score;
        const float loss_score = (-beta * S1 - (1.f - beta) * S2) * inv_m;
        const float loss_geo   = SG * inv_geo_div;  // LAMBDA_GEOMETRY = 1
        out[0] = loss_score + loss_geo;
    }
}

extern "C" void kernel_launch(void* const* d_in, const int* in_sizes, int n_in,
                              void* d_out, int out_size, void* d_ws, size_t ws_size,
                              hipStream_t stream) {
    const float4* yts = (const float4*)d_in[0];
    const float4* yps = (const float4*)d_in[1];
    const float4* ytg = (const float4*)d_in[2];
    const float4* ypg = (const float4*)d_in[3];
    float* out = (float*)d_out;
    float4* partial = (float4*)d_ws;

    const int n_score = in_sizes[0];          // m*1*H*W = 2,097,152
    const int n_geo   = in_sizes[2];          // m*8*H*W = 16,777,216
    const int n_s4 = n_score / 4;
    const int n_g4 = n_geo / 4;

    int blocks = 2048;                        // 8 blocks/CU, 32 waves/CU
    const size_t need = (size_t)blocks * sizeof(float4);
    if (ws_size < need) blocks = (int)(ws_size / sizeof(float4));  // safety

    // m=128; n_pix = m*H*W = n_score; divisor = n_c * n_pix = 8 * n_score
    const float inv_n_score = 1.f / (float)n_score;
    const float inv_m       = 1.f / 128.f;
    const float inv_geo_div = 1.f / (8.f * (float)n_score);

    loss_reduce<<<blocks, THREADS, 0, stream>>>(yts, yps, ytg, ypg, partial,
                                                n_s4, n_g4);
    loss_finalize<<<1, THREADS, 0, stream>>>(partial, blocks, out,
                                             inv_n_score, inv_m, inv_geo_div);
}